// Round 7
// baseline (130.673 us; speedup 1.0000x reference)
//
#include <hip/hip_runtime.h>
#include <math.h>

// NaiveDFTQNN: 25-wire state vector, DIM = 2^25.
// out = (cos(theta[0]/2)/||f||) * (tensor product of 12 Givens rotations) * f
// Pair j (j=0..11) acts on little-endian element bits (2j+1, 2j), angle theta[11-j]/2:
//   v=01: n01 = c*a01 - s*a10 ; v=10: n10 = s*a01 + c*a10 ; v=00,11 untouched.
// Bit 24 (wire 0) is a spectator (RX folds into the scalar).
//
// Pass order chosen for Infinity-Cache locality (r6 lesson: identical kernel runs
// 26 us on IC-hot data vs 80 us against HBM):
//   qnn_hi: j7..j11 (bits 14..23) + sumsq, in->out. NT-load in (no IC allocate),
//           regular store (intermediate stays IC-resident). 128 KB LDS tile,
//           128 B granules (full L2 lines). 2 tiles/block, B-loads prefetched
//           during A's LDS trips.
//   qnn_lo: j0..j6 (bits 0..13) + scale, in place on IC-hot out. Contiguous tile.

typedef float f32x4 __attribute__((ext_vector_type(4)));

static __device__ __forceinline__ float4 nt_load4(const float* p) {
    f32x4 v = __builtin_nontemporal_load((const f32x4*)p);
    return *(float4*)&v;
}

static __device__ __forceinline__ void rot4(float4& a, float4& b, float c, float s) {
    float4 na, nb;
    na.x = c*a.x - s*b.x;  nb.x = s*a.x + c*b.x;
    na.y = c*a.y - s*b.y;  nb.y = s*a.y + c*b.y;
    na.z = c*a.z - s*b.z;  nb.z = s*a.z + c*b.z;
    na.w = c*a.w - s*b.w;  nb.w = s*a.w + c*b.w;
    a = na; b = nb;
}

static __device__ __forceinline__ float4 shflx4(float4 v, int m) {
    float4 r;
    r.x = __shfl_xor(v.x, m, 64);
    r.y = __shfl_xor(v.y, m, 64);
    r.z = __shfl_xor(v.z, m, 64);
    r.w = __shfl_xor(v.w, m, 64);
    return r;
}

// Givens pair on lane bits (sh+1, sh), over NR float4 regs. Branchless per-lane (cl,sl).
template <int NR>
static __device__ __forceinline__ void rotshfl(float4* f, int sh, float c, float s, int lane) {
    const int pv = (lane >> sh) & 3;
    const bool act = (pv == 1) || (pv == 2);
    const float cl = act ? c : 1.0f;
    const float sl = act ? ((pv == 1) ? -s : s) : 0.0f;
    const int m = 3 << sh;
#pragma unroll
    for (int k = 0; k < NR; ++k) {
        float4 p = shflx4(f[k], m);
        float4 n;
        n.x = fmaf(sl, p.x, cl * f[k].x);
        n.y = fmaf(sl, p.y, cl * f[k].y);
        n.z = fmaf(sl, p.z, cl * f[k].z);
        n.w = fmaf(sl, p.w, cl * f[k].w);
        f[k] = n;
    }
}

// ---------------- qnn_hi: pairs j7..j11 (el bits 14..23) + sumsq, in -> out --------
// Tile: 1024 H-combos (el bits 14..23) x 32-float payload (el bits 0..4) = 128 KB.
// Block mid = el bits 5..13 (grid 512); both b24 values (tiles A/B) per block.
// Tile slot s (13 bits) = H<<3 | pq (pq = el bits 2..4).
// Global quad = b24<<22 | (s>>3)<<12 | mid<<3 | (s&7) -> 128 B granules, 64 KB stride.
// Gate bits on s: j7=(4,3) j8=(6,5) j9=(8,7) j10=(10,9) j11=(12,11).
// load (s = k<<10|t): j7 lane-shuffle, j11 k-regs; trip1: j8; trip2: j9; final: j10.
// All LDS maps keep slot congruent to lane mod >=32 -> conflict-free (measured 0).
__global__ __launch_bounds__(1024) void qnn_hi(const float* __restrict__ in,
                                               const float* __restrict__ theta,
                                               float* __restrict__ out,
                                               double* __restrict__ partials) {
    __shared__ __align__(16) float4 lds[8192];   // 128 KB
    __shared__ double red[16];
    const int t = threadIdx.x, lane = t & 63, w = t >> 6;
    const int mid = blockIdx.x;
    const long gqA = (long)mid << 3;                   // b24 = 0
    const long gqB = (1L << 22) | ((long)mid << 3);    // b24 = 1

    float c7,s7,c8,s8,c9,s9,c10,s10,c11,s11;
    { float th;
      th=0.5f*theta[4]; c7 =cosf(th); s7 =sinf(th);
      th=0.5f*theta[3]; c8 =cosf(th); s8 =sinf(th);
      th=0.5f*theta[2]; c9 =cosf(th); s9 =sinf(th);
      th=0.5f*theta[1]; c10=cosf(th); s10=sinf(th);
      th=0.5f*theta[0]; c11=cosf(th); s11=sinf(th); }

    double acc = 0.0;
    float4 f[8], g[8];

    // ---- tile A: load + j7/j11 + LDS write ----
#pragma unroll
    for (int k = 0; k < 8; ++k) {
        const int s_ = (k << 10) | t;
        f[k] = nt_load4(in + ((gqA | ((long)(s_ >> 3) << 12) | (s_ & 7)) << 2));
    }
#pragma unroll
    for (int k = 0; k < 8; ++k)
        acc += (double)f[k].x*f[k].x + (double)f[k].y*f[k].y
             + (double)f[k].z*f[k].z + (double)f[k].w*f[k].w;
    rotshfl<8>(f, 3, c7, s7, lane);
    rot4(f[2], f[4], c11, s11);
    rot4(f[3], f[5], c11, s11);
#pragma unroll
    for (int k = 0; k < 8; ++k) lds[(k << 10) | t] = f[k];
    __syncthreads();

    // ---- prefetch tile B (overlaps A's LDS trips up to the next barrier) ----
#pragma unroll
    for (int k = 0; k < 8; ++k) {
        const int s_ = (k << 10) | t;
        g[k] = nt_load4(in + ((gqB | ((long)(s_ >> 3) << 12) | (s_ & 7)) << 2));
    }

    {   // trip1 A: j8 (s bits 6,5 = b bits 1,0)
        const int base = ((lane >> 5) << 12) | (w << 8) | (lane & 31);
#pragma unroll
        for (int b = 0; b < 8; ++b) f[b] = lds[base | (b << 5)];
        rot4(f[1], f[2], c8, s8);
        rot4(f[5], f[6], c8, s8);
#pragma unroll
        for (int b = 0; b < 8; ++b) lds[base | (b << 5)] = f[b];
    }
    __syncthreads();
    {   // trip2 A: j9 (s bits 8,7 = b bits 1,0)
        const int base = ((w >> 1) << 10) | ((w & 1) << 6) | lane;
#pragma unroll
        for (int b = 0; b < 8; ++b) f[b] = lds[base | (b << 7)];
        rot4(f[1], f[2], c9, s9);
        rot4(f[5], f[6], c9, s9);
#pragma unroll
        for (int b = 0; b < 8; ++b) lds[base | (b << 7)] = f[b];
    }
    __syncthreads();
    {   // final A: j10 (s bits 10,9 = k bits 1,0) + store (regular: keep IC-resident)
        const int base = ((w >> 3) << 12) | ((w & 7) << 6) | lane;
#pragma unroll
        for (int k = 0; k < 8; ++k) f[k] = lds[base | (k << 9)];
        rot4(f[1], f[2], c10, s10);
        rot4(f[5], f[6], c10, s10);
#pragma unroll
        for (int k = 0; k < 8; ++k) {
            const int s_ = base | (k << 9);
            *(float4*)(out + ((gqA | ((long)(s_ >> 3) << 12) | (s_ & 7)) << 2)) = f[k];
        }
    }
    __syncthreads();

    // ---- tile B: same schedule on g ----
#pragma unroll
    for (int k = 0; k < 8; ++k)
        acc += (double)g[k].x*g[k].x + (double)g[k].y*g[k].y
             + (double)g[k].z*g[k].z + (double)g[k].w*g[k].w;
    rotshfl<8>(g, 3, c7, s7, lane);
    rot4(g[2], g[4], c11, s11);
    rot4(g[3], g[5], c11, s11);
#pragma unroll
    for (int k = 0; k < 8; ++k) lds[(k << 10) | t] = g[k];
    __syncthreads();
    {   // trip1 B
        const int base = ((lane >> 5) << 12) | (w << 8) | (lane & 31);
#pragma unroll
        for (int b = 0; b < 8; ++b) g[b] = lds[base | (b << 5)];
        rot4(g[1], g[2], c8, s8);
        rot4(g[5], g[6], c8, s8);
#pragma unroll
        for (int b = 0; b < 8; ++b) lds[base | (b << 5)] = g[b];
    }
    __syncthreads();
    {   // trip2 B
        const int base = ((w >> 1) << 10) | ((w & 1) << 6) | lane;
#pragma unroll
        for (int b = 0; b < 8; ++b) g[b] = lds[base | (b << 7)];
        rot4(g[1], g[2], c9, s9);
        rot4(g[5], g[6], c9, s9);
#pragma unroll
        for (int b = 0; b < 8; ++b) lds[base | (b << 7)] = g[b];
    }
    __syncthreads();
    {   // final B + store
        const int base = ((w >> 3) << 12) | ((w & 7) << 6) | lane;
#pragma unroll
        for (int k = 0; k < 8; ++k) g[k] = lds[base | (k << 9)];
        rot4(g[1], g[2], c10, s10);
        rot4(g[5], g[6], c10, s10);
#pragma unroll
        for (int k = 0; k < 8; ++k) {
            const int s_ = base | (k << 9);
            *(float4*)(out + ((gqB | ((long)(s_ >> 3) << 12) | (s_ & 7)) << 2)) = g[k];
        }
    }

    // ---- deterministic sumsq partial ----
#pragma unroll
    for (int off = 32; off > 0; off >>= 1) acc += __shfl_down(acc, off, 64);
    if (lane == 0) red[w] = acc;
    __syncthreads();
    if (t == 0) {
        double s = 0.0;
#pragma unroll
        for (int i = 0; i < 16; ++i) s += red[i];
        partials[mid] = s;
    }
}

// ---------------- Norm: 512 partials -> scale = cos(theta[0]/2)/sqrt(sum) ----------
__global__ void qnn_norm(const double* __restrict__ partials,
                         const float* __restrict__ theta,
                         double* __restrict__ scale) {
    __shared__ double w[4];
    const int t = threadIdx.x;
    double acc = 0.0;
    for (int i = t; i < 512; i += 256) acc += partials[i];
#pragma unroll
    for (int off = 32; off > 0; off >>= 1) acc += __shfl_down(acc, off, 64);
    if ((t & 63) == 0) w[t >> 6] = acc;
    __syncthreads();
    if (t == 0) {
        double tot = w[0] + w[1] + w[2] + w[3];
        *scale = (double)cosf(0.5f * theta[0]) / sqrt(tot);
    }
}

// ---------------- qnn_lo: pairs j0..j6 (el bits 0..13) + scale, in place -----------
// Contiguous 64 KB tile (4096 quads, slot bits 0..11 = el bits 2..13), IC-hot.
// j0: components. j1,j2,j3: lane shuffles. j4: slot bits 7,6 (trip 1).
// j5: slot bits 9,8 (trip 2 + scale + store). j6: slot bits 11,10 (k regs).
__global__ __launch_bounds__(1024, 8) void qnn_lo(float* __restrict__ buf,
                                                  const float* __restrict__ theta,
                                                  const double* __restrict__ scale) {
    __shared__ __align__(16) float4 lds[4096];
    const int t = threadIdx.x, lane = t & 63;
    const long gfb = (long)blockIdx.x << 12;   // quad base

    float c0,s0,c1,s1,c2,s2,c3,s3,c4,s4,c5,s5,c6,s6;
    { float th;
      th=0.5f*theta[11]; c0=cosf(th); s0=sinf(th);
      th=0.5f*theta[10]; c1=cosf(th); s1=sinf(th);
      th=0.5f*theta[9];  c2=cosf(th); s2=sinf(th);
      th=0.5f*theta[8];  c3=cosf(th); s3=sinf(th);
      th=0.5f*theta[7];  c4=cosf(th); s4=sinf(th);
      th=0.5f*theta[6];  c5=cosf(th); s5=sinf(th);
      th=0.5f*theta[5];  c6=cosf(th); s6=sinf(th); }
    const float sc = (float)(*scale);

    float4 f[4];
#pragma unroll
    for (int k = 0; k < 4; ++k)
        f[k] = *(const float4*)(buf + ((gfb + k*1024 + t) << 2));
    // j0: el bits (1,0) = components (y,z)
#pragma unroll
    for (int k = 0; k < 4; ++k) {
        float ny = c0*f[k].y - s0*f[k].z;
        float nz = s0*f[k].y + c0*f[k].z;
        f[k].y = ny; f[k].z = nz;
    }
    rotshfl<4>(f, 0, c1, s1, lane);  // j1: slot bits 1,0
    rotshfl<4>(f, 2, c2, s2, lane);  // j2: slot bits 3,2
    rotshfl<4>(f, 4, c3, s3, lane);  // j3: slot bits 5,4
    rot4(f[1], f[2], c6, s6);        // j6: slot bits 11,10 = k

#pragma unroll
    for (int k = 0; k < 4; ++k) lds[k*1024 + t] = f[k];
    __syncthreads();
    {   // j4: slot bits 7,6
        const int sb = ((t >> 6) << 8) | (t & 63);
#pragma unroll
        for (int b = 0; b < 4; ++b) f[b] = lds[sb | (b << 6)];
        rot4(f[1], f[2], c4, s4);
#pragma unroll
        for (int b = 0; b < 4; ++b) lds[sb | (b << 6)] = f[b];
    }
    __syncthreads();
    {   // j5: slot bits 9,8 + scale + store
        const int sb = ((t >> 8) << 10) | (t & 255);
#pragma unroll
        for (int b = 0; b < 4; ++b) f[b] = lds[sb | (b << 8)];
        rot4(f[1], f[2], c5, s5);
#pragma unroll
        for (int b = 0; b < 4; ++b) {
            float4 v = f[b];
            v.x *= sc; v.y *= sc; v.z *= sc; v.w *= sc;
            *(float4*)(buf + ((gfb + (sb | (b << 8))) << 2)) = v;
        }
    }
}

extern "C" void kernel_launch(void* const* d_in, const int* in_sizes, int n_in,
                              void* d_out, int out_size, void* d_ws, size_t ws_size,
                              hipStream_t stream) {
    const float* in = (const float*)d_in[0];      // feature, 2^25 f32
    const float* theta = (const float*)d_in[1];   // 13 f32
    float* out = (float*)d_out;                   // 2^25 f32
    double* part = (double*)d_ws;                 // 512 partials + 1 scale
    double* scale = part + 512;

    qnn_hi<<<512, 1024, 0, stream>>>(in, theta, out, part);
    qnn_norm<<<1, 256, 0, stream>>>(part, theta, scale);
    qnn_lo<<<2048, 1024, 0, stream>>>(out, theta, scale);
}

// Round 8
// 104.458 us; speedup vs baseline: 1.2510x; 1.2510x over previous
//
#include <hip/hip_runtime.h>
#include <math.h>

// NaiveDFTQNN: 25-wire state vector, DIM = 2^25.
// out = (cos(theta[0]/2)/||f||) * (tensor product of 12 Givens rotations) * f
// Pair j (j=0..11) acts on little-endian element bits (2j+1, 2j), angle theta[11-j]/2:
//   v=01: n01 = c*a01 - s*a10 ; v=10: n10 = s*a01 + c*a10 ; v=00,11 untouched.
// Bit 24 (wire 0) is a spectator (RX folds into the scalar).
//
// Structure (r6 ordering, IC-steered):
//   qnn_p1:  j0..j6 (el bits 0..13) + sumsq, in -> out. NT-load in (no IC
//            allocate), regular store (intermediate stays IC-resident).
//            NEW: 256 thr x 16 float4/thread, ONE LDS round trip, ONE barrier,
//            16-deep load ILP (attacks the phase-serialization that held the
//            in->out leg at 3.5 TB/s vs 6.3 TB/s copy ceiling).
//   qnn_high: j7..j11 (el bits 14..23) + scale, in place on IC-hot out,
//            128 KB LDS tile, 128 B granules, NT final store. (r6, 40 us)

typedef float f32x4 __attribute__((ext_vector_type(4)));

static __device__ __forceinline__ float4 nt_load4(const float* p) {
    f32x4 v = __builtin_nontemporal_load((const f32x4*)p);
    return *(float4*)&v;
}
static __device__ __forceinline__ void nt_store4(float* p, float4 v) {
    __builtin_nontemporal_store(*(f32x4*)&v, (f32x4*)p);
}

static __device__ __forceinline__ void rot4(float4& a, float4& b, float c, float s) {
    float4 na, nb;
    na.x = c*a.x - s*b.x;  nb.x = s*a.x + c*b.x;
    na.y = c*a.y - s*b.y;  nb.y = s*a.y + c*b.y;
    na.z = c*a.z - s*b.z;  nb.z = s*a.z + c*b.z;
    na.w = c*a.w - s*b.w;  nb.w = s*a.w + c*b.w;
    a = na; b = nb;
}

static __device__ __forceinline__ float4 shflx4(float4 v, int m) {
    float4 r;
    r.x = __shfl_xor(v.x, m, 64);
    r.y = __shfl_xor(v.y, m, 64);
    r.z = __shfl_xor(v.z, m, 64);
    r.w = __shfl_xor(v.w, m, 64);
    return r;
}

// Givens pair on lane bits (sh+1, sh), over NR float4 regs. Branchless per-lane (cl,sl).
template <int NR>
static __device__ __forceinline__ void rotshfl(float4* f, int sh, float c, float s, int lane) {
    const int pv = (lane >> sh) & 3;
    const bool act = (pv == 1) || (pv == 2);
    const float cl = act ? c : 1.0f;
    const float sl = act ? ((pv == 1) ? -s : s) : 0.0f;
    const int m = 3 << sh;
#pragma unroll
    for (int k = 0; k < NR; ++k) {
        float4 p = shflx4(f[k], m);
        float4 n;
        n.x = fmaf(sl, p.x, cl * f[k].x);
        n.y = fmaf(sl, p.y, cl * f[k].y);
        n.z = fmaf(sl, p.z, cl * f[k].z);
        n.w = fmaf(sl, p.w, cl * f[k].w);
        f[k] = n;
    }
}

// ---------------- qnn_p1: pairs j0..j6 (el bits 0..13), in -> out, + partials ------
// Tile = contiguous 16384 floats = 4096 quads (quad-index s bits 0..11 = el bits 2..13).
// 256 threads, 16 quads/thread (all in registers).
// Load layout:  s = w2<<10 | k<<6 | lane   (w2 = t>>6, k = reg 0..15, lane = t&63)
//   -> j0: components (el 1,0); j1/j2/j3: lane shfl (s bits 1,0/3,2/5,4);
//      j4: s bits 7,6 = k bits 1,0 (regs); j5: s bits 9,8 = k bits 3,2 (regs).
// One LDS round trip to layout: s' = m<<8 | w2<<6 | lane  (m = reg 0..15)
//   -> j6: s bits 11,10 = m bits 3,2 (regs). Then coalesced store at s'.
// Both LDS access patterns are lane-contiguous b128 -> conflict-free.
__global__ __launch_bounds__(256, 2) void qnn_p1(const float* __restrict__ in,
                                                 const float* __restrict__ theta,
                                                 float* __restrict__ out,
                                                 double* __restrict__ partials) {
    __shared__ __align__(16) float4 lds[4096];   // 64 KB
    __shared__ double red[4];
    const int t = threadIdx.x, lane = t & 63, w2 = t >> 6;
    const long gfb = (long)blockIdx.x << 12;     // quad base

    float c0,s0,c1,s1,c2,s2,c3,s3,c4,s4,c5,s5,c6,s6;
    { float th;
      th=0.5f*theta[11]; c0=cosf(th); s0=sinf(th);
      th=0.5f*theta[10]; c1=cosf(th); s1=sinf(th);
      th=0.5f*theta[9];  c2=cosf(th); s2=sinf(th);
      th=0.5f*theta[8];  c3=cosf(th); s3=sinf(th);
      th=0.5f*theta[7];  c4=cosf(th); s4=sinf(th);
      th=0.5f*theta[6];  c5=cosf(th); s5=sinf(th);
      th=0.5f*theta[5];  c6=cosf(th); s6=sinf(th); }

    float4 f[16];
    // ---- load phase: 16 outstanding NT dwordx4 per thread ----
#pragma unroll
    for (int k = 0; k < 16; ++k) {
        const int s_ = (w2 << 10) | (k << 6) | lane;
        f[k] = nt_load4(in + ((gfb + s_) << 2));
    }
    double acc = 0.0;
#pragma unroll
    for (int k = 0; k < 16; ++k)
        acc += (double)f[k].x*f[k].x + (double)f[k].y*f[k].y
             + (double)f[k].z*f[k].z + (double)f[k].w*f[k].w;

    // ---- register rotations ----
    // j0: el bits (1,0) = components (y,z)
#pragma unroll
    for (int k = 0; k < 16; ++k) {
        float ny = c0*f[k].y - s0*f[k].z;
        float nz = s0*f[k].y + c0*f[k].z;
        f[k].y = ny; f[k].z = nz;
    }
    rotshfl<16>(f, 0, c1, s1, lane);   // j1: s bits 1,0
    rotshfl<16>(f, 2, c2, s2, lane);   // j2: s bits 3,2
    rotshfl<16>(f, 4, c3, s3, lane);   // j3: s bits 5,4
#pragma unroll
    for (int hi = 0; hi < 16; hi += 4)                 // j4: k bits 1,0
        rot4(f[hi + 1], f[hi + 2], c4, s4);
#pragma unroll
    for (int lo = 0; lo < 4; ++lo)                     // j5: k bits 3,2
        rot4(f[4 + lo], f[8 + lo], c5, s5);

    // ---- one LDS round trip: exchange to s' = m<<8 | w2<<6 | lane ----
#pragma unroll
    for (int k = 0; k < 16; ++k)
        lds[(w2 << 10) | (k << 6) | lane] = f[k];
    __syncthreads();
#pragma unroll
    for (int m = 0; m < 16; ++m)
        f[m] = lds[(m << 8) | (w2 << 6) | lane];
#pragma unroll
    for (int lo = 0; lo < 4; ++lo)                     // j6: m bits 3,2
        rot4(f[4 + lo], f[8 + lo], c6, s6);

    // ---- store phase (regular: keep intermediate IC-resident) ----
#pragma unroll
    for (int m = 0; m < 16; ++m) {
        const int s_ = (m << 8) | (w2 << 6) | lane;
        *(float4*)(out + ((gfb + s_) << 2)) = f[m];
    }

    // ---- deterministic sumsq partial ----
#pragma unroll
    for (int off = 32; off > 0; off >>= 1) acc += __shfl_down(acc, off, 64);
    if (lane == 0) red[w2] = acc;
    __syncthreads();
    if (t == 0)
        partials[blockIdx.x] = red[0] + red[1] + red[2] + red[3];
}

// ---------------- Norm: 2048 partials -> scale = cos(theta[0]/2)/sqrt(sum) ---------
__global__ void qnn_norm(const double* __restrict__ partials,
                         const float* __restrict__ theta,
                         double* __restrict__ scale) {
    __shared__ double w[4];
    const int t = threadIdx.x;
    double acc = 0.0;
    for (int i = t; i < 2048; i += 256) acc += partials[i];
#pragma unroll
    for (int off = 32; off > 0; off >>= 1) acc += __shfl_down(acc, off, 64);
    if ((t & 63) == 0) w[t >> 6] = acc;
    __syncthreads();
    if (t == 0) {
        double tot = w[0] + w[1] + w[2] + w[3];
        *scale = (double)cosf(0.5f * theta[0]) / sqrt(tot);
    }
}

// ---------------- qnn_high: pairs j7..j11 (el bits 14..23) + scale, in place -------
// Tile: 1024 H-combos (el bits 14..23) x 32-float payload (el bits 0..4) = 128 KB.
// Element addr = b24<<24 | H<<14 | mid<<5 | p5;  block id = b24<<9 | mid (1024 blocks).
// Tile slot s (13 bits) = H<<3 | pq (pq = el bits 2..4).
// Global quad = b24<<22 | (s>>3)<<12 | mid<<3 | (s&7) -> 128 B granules, 64 KB stride.
// Gate bits on s: j7=(4,3) j8=(6,5) j9=(8,7) j10=(10,9) j11=(12,11).
// load (s = k<<10|t): j7 lane-shuffle, j11 k-regs; trip1: j8; trip2: j9;
// final: j10 + scale + NT store. All LDS maps conflict-free (measured 0).
__global__ __launch_bounds__(1024, 4) void qnn_high(float* __restrict__ buf,
                                                    const float* __restrict__ theta,
                                                    const double* __restrict__ scale) {
    __shared__ __align__(16) float4 lds[8192];   // 128 KB
    const int t = threadIdx.x, lane = t & 63, w = t >> 6;
    const int bid = blockIdx.x;
    const int b24 = bid >> 9, mid = bid & 511;
    const long gq = ((long)b24 << 22) | ((long)mid << 3);   // quad base

    float c7,s7,c8,s8,c9,s9,c10,s10,c11,s11;
    { float th;
      th=0.5f*theta[4]; c7 =cosf(th); s7 =sinf(th);
      th=0.5f*theta[3]; c8 =cosf(th); s8 =sinf(th);
      th=0.5f*theta[2]; c9 =cosf(th); s9 =sinf(th);
      th=0.5f*theta[1]; c10=cosf(th); s10=sinf(th);
      th=0.5f*theta[0]; c11=cosf(th); s11=sinf(th); }
    const float sc = (float)(*scale);

    float4 f[8];
    // ---- load: s = k<<10 | t ----
#pragma unroll
    for (int k = 0; k < 8; ++k) {
        const int s_ = (k << 10) | t;
        f[k] = *(const float4*)(buf + ((gq | ((long)(s_ >> 3) << 12) | (s_ & 7)) << 2));
    }
    rotshfl<8>(f, 3, c7, s7, lane);          // j7: s bits 4,3 = lane bits 4,3
    rot4(f[2], f[4], c11, s11);              // j11: s bits 12,11 = k bits 2,1
    rot4(f[3], f[5], c11, s11);
#pragma unroll
    for (int k = 0; k < 8; ++k) lds[(k << 10) | t] = f[k];
    __syncthreads();

    {   // ---- trip1: j8 (s bits 6,5 = b bits 1,0) ----
        const int base = ((lane >> 5) << 12) | (w << 8) | (lane & 31);
#pragma unroll
        for (int b = 0; b < 8; ++b) f[b] = lds[base | (b << 5)];
        rot4(f[1], f[2], c8, s8);
        rot4(f[5], f[6], c8, s8);
#pragma unroll
        for (int b = 0; b < 8; ++b) lds[base | (b << 5)] = f[b];
    }
    __syncthreads();

    {   // ---- trip2: j9 (s bits 8,7 = b bits 1,0) ----
        const int base = ((w >> 1) << 10) | ((w & 1) << 6) | lane;
#pragma unroll
        for (int b = 0; b < 8; ++b) f[b] = lds[base | (b << 7)];
        rot4(f[1], f[2], c9, s9);
        rot4(f[5], f[6], c9, s9);
#pragma unroll
        for (int b = 0; b < 8; ++b) lds[base | (b << 7)] = f[b];
    }
    __syncthreads();

    {   // ---- final: j10 (s bits 10,9 = k bits 1,0) + scale + NT store ----
        const int base = ((w >> 3) << 12) | ((w & 7) << 6) | lane;
#pragma unroll
        for (int k = 0; k < 8; ++k) f[k] = lds[base | (k << 9)];
        rot4(f[1], f[2], c10, s10);
        rot4(f[5], f[6], c10, s10);
#pragma unroll
        for (int k = 0; k < 8; ++k) {
            const int s_ = base | (k << 9);
            float4 v = f[k];
            v.x *= sc; v.y *= sc; v.z *= sc; v.w *= sc;
            nt_store4(buf + ((gq | ((long)(s_ >> 3) << 12) | (s_ & 7)) << 2), v);
        }
    }
}

extern "C" void kernel_launch(void* const* d_in, const int* in_sizes, int n_in,
                              void* d_out, int out_size, void* d_ws, size_t ws_size,
                              hipStream_t stream) {
    const float* in = (const float*)d_in[0];      // feature, 2^25 f32
    const float* theta = (const float*)d_in[1];   // 13 f32
    float* out = (float*)d_out;                   // 2^25 f32
    double* part = (double*)d_ws;                 // 2048 partials + 1 scale
    double* scale = part + 2048;

    qnn_p1<<<2048, 256, 0, stream>>>(in, theta, out, part);
    qnn_norm<<<1, 256, 0, stream>>>(part, theta, scale);
    qnn_high<<<1024, 1024, 0, stream>>>(out, theta, scale);
}

// Round 9
// 97.959 us; speedup vs baseline: 1.3340x; 1.0663x over previous
//
#include <hip/hip_runtime.h>
#include <math.h>

// NaiveDFTQNN: 25-wire state vector, DIM = 2^25.
// out = (cos(theta[0]/2)/||f||) * (tensor product of 12 Givens rotations) * f
// Pair j (j=0..11) acts on little-endian element bits (2j+1, 2j), angle theta[11-j]/2:
//   v=01: n01 = c*a01 - s*a10 ; v=10: n10 = s*a01 + c*a10 ; v=00,11 untouched.
// Bit 24 (wire 0) is a spectator (RX folds into the scalar).
//
// Structure (IC-steered, both kernels 2-tile software-pipelined with raw
// lgkm-only barriers so prefetched global loads stay in flight across them):
//   qnn_p1:  j0..j6 (el bits 0..13) + sumsq, in -> out. NT-load in, regular
//            store (intermediate stays IC-resident). 256 thr x 16 quads x 2 tiles.
//   qnn_high: j7..j11 (el bits 14..23) + scale, out in place. 512 thr x 16 quads
//            x 2 tiles (b24=0/1), 128 KB LDS, 1 LDS trip, NT final store.

typedef float f32x4 __attribute__((ext_vector_type(4)));

static __device__ __forceinline__ float4 nt_load4(const float* p) {
    f32x4 v = __builtin_nontemporal_load((const f32x4*)p);
    return *(float4*)&v;
}
static __device__ __forceinline__ void nt_store4(float* p, float4 v) {
    __builtin_nontemporal_store(*(f32x4*)&v, (f32x4*)p);
}

// Barrier that drains ONLY lgkmcnt (LDS) — global loads/stores stay in flight.
// ("memory" clobber pins memory-op ordering; HIP-level ds ops get compiler waits.)
static __device__ __forceinline__ void bar_lgkm() {
    asm volatile("s_waitcnt lgkmcnt(0)\n\ts_barrier" ::: "memory");
}

static __device__ __forceinline__ void rot4(float4& a, float4& b, float c, float s) {
    float4 na, nb;
    na.x = c*a.x - s*b.x;  nb.x = s*a.x + c*b.x;
    na.y = c*a.y - s*b.y;  nb.y = s*a.y + c*b.y;
    na.z = c*a.z - s*b.z;  nb.z = s*a.z + c*b.z;
    na.w = c*a.w - s*b.w;  nb.w = s*a.w + c*b.w;
    a = na; b = nb;
}

static __device__ __forceinline__ float4 shflx4(float4 v, int m) {
    float4 r;
    r.x = __shfl_xor(v.x, m, 64);
    r.y = __shfl_xor(v.y, m, 64);
    r.z = __shfl_xor(v.z, m, 64);
    r.w = __shfl_xor(v.w, m, 64);
    return r;
}

template <int NR>
static __device__ __forceinline__ void rotshfl(float4* f, int sh, float c, float s, int lane) {
    const int pv = (lane >> sh) & 3;
    const bool act = (pv == 1) || (pv == 2);
    const float cl = act ? c : 1.0f;
    const float sl = act ? ((pv == 1) ? -s : s) : 0.0f;
    const int m = 3 << sh;
#pragma unroll
    for (int k = 0; k < NR; ++k) {
        float4 p = shflx4(f[k], m);
        float4 n;
        n.x = fmaf(sl, p.x, cl * f[k].x);
        n.y = fmaf(sl, p.y, cl * f[k].y);
        n.z = fmaf(sl, p.z, cl * f[k].z);
        n.w = fmaf(sl, p.w, cl * f[k].w);
        f[k] = n;
    }
}

// ---------------- qnn_p1: pairs j0..j6 (el bits 0..13), in -> out, + partials ------
// Tile = contiguous 4096 quads (s bits 0..11 = el bits 2..13); 2 tiles/block.
// Load layout  s = w2<<10 | k<<6 | lane: j0 components; j1/j2/j3 lane shfl
// (s bits 1,0/3,2/5,4); j4 = k bits 1,0; j5 = k bits 3,2.
// LDS exchange to s' = m<<8 | w2<<6 | lane: j6 = m bits 3,2. Store at s'.
// Pipeline: loadA,loadB | rotA,writeA | BAR | readA,j6A,storeA,rotB | BAR |
//           writeB | BAR | readB,j6B,storeB.  (BAR = lgkm-only)
__global__ __launch_bounds__(256, 2) void qnn_p1(const float* __restrict__ in,
                                                 const float* __restrict__ theta,
                                                 float* __restrict__ out,
                                                 double* __restrict__ partials) {
    __shared__ __align__(16) float4 lds[4096];   // 64 KB
    __shared__ double red[4];
    const int t = threadIdx.x, lane = t & 63, w2 = t >> 6;
    const long gA = (long)blockIdx.x << 13;      // quad base, tile A
    const long gB = gA + 4096;                   // tile B

    float c0,s0,c1,s1,c2,s2,c3,s3,c4,s4,c5,s5,c6,s6;
    { float th;
      th=0.5f*theta[11]; c0=cosf(th); s0=sinf(th);
      th=0.5f*theta[10]; c1=cosf(th); s1=sinf(th);
      th=0.5f*theta[9];  c2=cosf(th); s2=sinf(th);
      th=0.5f*theta[8];  c3=cosf(th); s3=sinf(th);
      th=0.5f*theta[7];  c4=cosf(th); s4=sinf(th);
      th=0.5f*theta[6];  c5=cosf(th); s5=sinf(th);
      th=0.5f*theta[5];  c6=cosf(th); s6=sinf(th); }

    float4 f[16], g[16];
    // ---- issue ALL 32 loads (B's stay in flight deep into A's processing) ----
#pragma unroll
    for (int k = 0; k < 16; ++k)
        f[k] = nt_load4(in + ((gA + ((w2 << 10) | (k << 6) | lane)) << 2));
#pragma unroll
    for (int k = 0; k < 16; ++k)
        g[k] = nt_load4(in + ((gB + ((w2 << 10) | (k << 6) | lane)) << 2));

    double acc = 0.0;
#pragma unroll
    for (int k = 0; k < 16; ++k)
        acc += (double)f[k].x*f[k].x + (double)f[k].y*f[k].y
             + (double)f[k].z*f[k].z + (double)f[k].w*f[k].w;

    // ---- tile A: register rotations j0..j5 ----
#pragma unroll
    for (int k = 0; k < 16; ++k) {
        float ny = c0*f[k].y - s0*f[k].z;
        float nz = s0*f[k].y + c0*f[k].z;
        f[k].y = ny; f[k].z = nz;
    }
    rotshfl<16>(f, 0, c1, s1, lane);
    rotshfl<16>(f, 2, c2, s2, lane);
    rotshfl<16>(f, 4, c3, s3, lane);
#pragma unroll
    for (int hi = 0; hi < 16; hi += 4) rot4(f[hi+1], f[hi+2], c4, s4);
#pragma unroll
    for (int lo = 0; lo < 4; ++lo)     rot4(f[4+lo], f[8+lo], c5, s5);

#pragma unroll
    for (int k = 0; k < 16; ++k) lds[(w2 << 10) | (k << 6) | lane] = f[k];
    bar_lgkm();
    // ---- read A at s' = m<<8 | w2<<6 | lane; j6 = m bits 3,2; store ----
#pragma unroll
    for (int m = 0; m < 16; ++m) f[m] = lds[(m << 8) | (w2 << 6) | lane];
#pragma unroll
    for (int lo = 0; lo < 4; ++lo) rot4(f[4+lo], f[8+lo], c6, s6);
#pragma unroll
    for (int m = 0; m < 16; ++m)
        *(float4*)(out + ((gA + ((m << 8) | (w2 << 6) | lane)) << 2)) = f[m];

    // ---- tile B register rotations (loads long since landed) ----
#pragma unroll
    for (int k = 0; k < 16; ++k)
        acc += (double)g[k].x*g[k].x + (double)g[k].y*g[k].y
             + (double)g[k].z*g[k].z + (double)g[k].w*g[k].w;
#pragma unroll
    for (int k = 0; k < 16; ++k) {
        float ny = c0*g[k].y - s0*g[k].z;
        float nz = s0*g[k].y + c0*g[k].z;
        g[k].y = ny; g[k].z = nz;
    }
    rotshfl<16>(g, 0, c1, s1, lane);
    rotshfl<16>(g, 2, c2, s2, lane);
    rotshfl<16>(g, 4, c3, s3, lane);
#pragma unroll
    for (int hi = 0; hi < 16; hi += 4) rot4(g[hi+1], g[hi+2], c4, s4);
#pragma unroll
    for (int lo = 0; lo < 4; ++lo)     rot4(g[4+lo], g[8+lo], c5, s5);

    bar_lgkm();   // all waves done reading A's LDS image
#pragma unroll
    for (int k = 0; k < 16; ++k) lds[(w2 << 10) | (k << 6) | lane] = g[k];
    bar_lgkm();
#pragma unroll
    for (int m = 0; m < 16; ++m) g[m] = lds[(m << 8) | (w2 << 6) | lane];
#pragma unroll
    for (int lo = 0; lo < 4; ++lo) rot4(g[4+lo], g[8+lo], c6, s6);
#pragma unroll
    for (int m = 0; m < 16; ++m)
        *(float4*)(out + ((gB + ((m << 8) | (w2 << 6) | lane)) << 2)) = g[m];

    // ---- deterministic sumsq partial ----
#pragma unroll
    for (int off = 32; off > 0; off >>= 1) acc += __shfl_down(acc, off, 64);
    if (lane == 0) red[w2] = acc;
    bar_lgkm();
    if (t == 0)
        partials[blockIdx.x] = red[0] + red[1] + red[2] + red[3];
}

// ---------------- Norm: 1024 partials -> scale = cos(theta[0]/2)/sqrt(sum) ---------
__global__ void qnn_norm(const double* __restrict__ partials,
                         const float* __restrict__ theta,
                         double* __restrict__ scale) {
    __shared__ double w[4];
    const int t = threadIdx.x;
    double acc = 0.0;
    for (int i = t; i < 1024; i += 256) acc += partials[i];
#pragma unroll
    for (int off = 32; off > 0; off >>= 1) acc += __shfl_down(acc, off, 64);
    if ((t & 63) == 0) w[t >> 6] = acc;
    __syncthreads();
    if (t == 0) {
        double tot = w[0] + w[1] + w[2] + w[3];
        *scale = (double)cosf(0.5f * theta[0]) / sqrt(tot);
    }
}

// ---------------- qnn_high: pairs j7..j11 (el bits 14..23) + scale, in place -------
// Tile: slot s (13 bits) = H<<3 | pq; H = el bits 14..23, pq = el bits 2..4.
// Global quad = b24<<22 | H<<12 | mid<<3 | pq (mid = el bits 5..13, grid 512;
// both b24 tiles per block). 128 B granules at 64 KB stride.
// Load layout s = k<<9 | t (512 thr, k=0..15): j7 = s bits 4,3 (lane shfl);
// j10 = s bits 10,9 = k bits 1,0; j11 = s bits 12,11 = k bits 3,2.
// LDS exchange to s' = w3<<10 | (lane>>5)<<9 | m<<5 | (lane&31):
// j8 = s bits 6,5 = m bits 1,0; j9 = s bits 8,7 = m bits 3,2. NT store at s'.
__global__ __launch_bounds__(512, 2) void qnn_high(float* __restrict__ buf,
                                                   const float* __restrict__ theta,
                                                   const double* __restrict__ scale) {
    __shared__ __align__(16) float4 lds[8192];   // 128 KB
    const int t = threadIdx.x, lane = t & 63, w3 = t >> 6;
    const int mid = blockIdx.x;
    const long gqA = (long)mid << 3;                 // b24 = 0
    const long gqB = (1L << 22) | ((long)mid << 3);  // b24 = 1

    float c7,s7,c8,s8,c9,s9,c10,s10,c11,s11;
    { float th;
      th=0.5f*theta[4]; c7 =cosf(th); s7 =sinf(th);
      th=0.5f*theta[3]; c8 =cosf(th); s8 =sinf(th);
      th=0.5f*theta[2]; c9 =cosf(th); s9 =sinf(th);
      th=0.5f*theta[1]; c10=cosf(th); s10=sinf(th);
      th=0.5f*theta[0]; c11=cosf(th); s11=sinf(th); }
    const float sc = (float)(*scale);

    const int rbase = (w3 << 10) | ((lane >> 5) << 9) | (lane & 31);  // read base

    float4 f[16], g[16];
    // ---- issue ALL 32 loads ----
#pragma unroll
    for (int k = 0; k < 16; ++k) {
        const int s_ = (k << 9) | t;
        f[k] = *(const float4*)(buf + ((gqA | ((long)(s_ >> 3) << 12) | (s_ & 7)) << 2));
    }
#pragma unroll
    for (int k = 0; k < 16; ++k) {
        const int s_ = (k << 9) | t;
        g[k] = *(const float4*)(buf + ((gqB | ((long)(s_ >> 3) << 12) | (s_ & 7)) << 2));
    }

    // ---- tile A: j7 (shfl), j10/j11 (regs) ----
    rotshfl<16>(f, 3, c7, s7, lane);
#pragma unroll
    for (int hi = 0; hi < 16; hi += 4) rot4(f[hi+1], f[hi+2], c10, s10);
#pragma unroll
    for (int lo = 0; lo < 4; ++lo)     rot4(f[4+lo], f[8+lo], c11, s11);
#pragma unroll
    for (int k = 0; k < 16; ++k) lds[(k << 9) | t] = f[k];
    bar_lgkm();
    // ---- read A; j8/j9 (regs); scale; NT store ----
#pragma unroll
    for (int m = 0; m < 16; ++m) f[m] = lds[rbase | (m << 5)];
#pragma unroll
    for (int hi = 0; hi < 16; hi += 4) rot4(f[hi+1], f[hi+2], c8, s8);
#pragma unroll
    for (int lo = 0; lo < 4; ++lo)     rot4(f[4+lo], f[8+lo], c9, s9);
#pragma unroll
    for (int m = 0; m < 16; ++m) {
        const int s_ = rbase | (m << 5);
        float4 v = f[m];
        v.x *= sc; v.y *= sc; v.z *= sc; v.w *= sc;
        nt_store4(buf + ((gqA | ((long)(s_ >> 3) << 12) | (s_ & 7)) << 2), v);
    }

    // ---- tile B ----
    rotshfl<16>(g, 3, c7, s7, lane);
#pragma unroll
    for (int hi = 0; hi < 16; hi += 4) rot4(g[hi+1], g[hi+2], c10, s10);
#pragma unroll
    for (int lo = 0; lo < 4; ++lo)     rot4(g[4+lo], g[8+lo], c11, s11);
    bar_lgkm();   // all waves done reading A's LDS image
#pragma unroll
    for (int k = 0; k < 16; ++k) lds[(k << 9) | t] = g[k];
    bar_lgkm();
#pragma unroll
    for (int m = 0; m < 16; ++m) g[m] = lds[rbase | (m << 5)];
#pragma unroll
    for (int hi = 0; hi < 16; hi += 4) rot4(g[hi+1], g[hi+2], c8, s8);
#pragma unroll
    for (int lo = 0; lo < 4; ++lo)     rot4(g[4+lo], g[8+lo], c9, s9);
#pragma unroll
    for (int m = 0; m < 16; ++m) {
        const int s_ = rbase | (m << 5);
        float4 v = g[m];
        v.x *= sc; v.y *= sc; v.z *= sc; v.w *= sc;
        nt_store4(buf + ((gqB | ((long)(s_ >> 3) << 12) | (s_ & 7)) << 2), v);
    }
}

extern "C" void kernel_launch(void* const* d_in, const int* in_sizes, int n_in,
                              void* d_out, int out_size, void* d_ws, size_t ws_size,
                              hipStream_t stream) {
    const float* in = (const float*)d_in[0];      // feature, 2^25 f32
    const float* theta = (const float*)d_in[1];   // 13 f32
    float* out = (float*)d_out;                   // 2^25 f32
    double* part = (double*)d_ws;                 // 1024 partials + 1 scale
    double* scale = part + 1024;

    qnn_p1<<<1024, 256, 0, stream>>>(in, theta, out, part);
    qnn_norm<<<1, 256, 0, stream>>>(part, theta, scale);
    qnn_high<<<512, 512, 0, stream>>>(out, theta, scale);
}